// Round 12
// baseline (25408.917 us; speedup 1.0000x reference)
//
#include <hip/hip_runtime.h>
#include <math.h>

// PixelQueryNet v11: lane = pixel, wave = cell, weights via LDS broadcast.
// Register-state design (act[64]+y[64] in VGPRs, no LDS activation traffic).
//
// R9/R10/R11 lesson: the AMDGPU allocator kept choosing 128 VGPRs (4 waves/EU
// occupancy target) and spilling the 128-float state to scratch (24 GB HBM
// write traffic) regardless of __launch_bounds__ minimums. Fix here:
// amdgpu_waves_per_eu(2,2) pins the band so the budget is 512/2 = 256 VGPRs,
// plus 256-thread blocks (the only shape that empirically allocated >128).
//
// Per low-res cell (b,i,j): MLP 4->64->64->64->64->3 (leaky 0.01, tanh) on the
// 64 pixels of its 8x8 tile; weights from lr_params[b,c,i,j] (channel stride
// PLANE=4096 floats).
//
// Block = 256 threads = 4 waves = 4 cells (one j-quad). Lane = pixel.
// Weights are wave-uniform: staged cooperatively into LDS [j][ch] chunks
// (1024 ch x 4 j, double-buffered; b32 loads -> 16 lines/inst, issued 16-deep;
// siblings n,n+8,n+16,n+24 on one XCD cover each 64B line -> FETCH ideal,
// proven R4-R8), consumed via same-address ds_read_b128 broadcasts (free).
// 13 barriers total. LDS ~44 KB -> 2 blocks/CU at 2 waves/SIMD.

static constexpr int PLANE = 4096;
static constexpr int NPAR  = 12995;
static constexpr int CHROW = 1032;   // chunk row stride (words)
static constexpr int SMROW = 712;    // smalls row stride (words)

__device__ __forceinline__ float leaky(float v) { return fmaxf(v, 0.01f * v); }

__global__ __launch_bounds__(256)
__attribute__((amdgpu_waves_per_eu(2, 2)))
void pqn(const float* __restrict__ lr, float* __restrict__ out) {
  __shared__ alignas(16) float CH[2][4 * CHROW];  // 33024 B  weight chunks
  __shared__ alignas(16) float SM[4 * SMROW];     // 11392 B  bias/L0/L4 region

  const int tid  = threadIdx.x;
  const int w    = tid >> 6;          // wave id = cell within j-quad
  const int lane = tid & 63;          // pixel
  const int dx = lane & 7, dy = lane >> 3;

  const int sch = tid >> 2;           // staging channel-offset 0..63
  const int sj  = tid & 3;            // staging j 0..3

  // ---- swizzle: 4 siblings (same XCD) cover one 64B weight line (R4-R8)
  const int n  = blockIdx.x;
  const int e2 = (n >> 3) & 3;
  const int P  = (n & 7) | ((n >> 5) << 3);   // 0..511
  const int jg = ((P & 3) << 2) | e2;         // 0..15 (j-quad)
  const int i  = (P >> 2) & 63;
  const int b  = (P >> 8) & 1;

  const float* __restrict__ gbase =
      lr + (size_t)b * NPAR * PLANE + (size_t)(i * 64 + jg * 4);

  // ---- prologue staging: smalls (L0 + hidden biases + L4^T) and chunk 0.
  // smalls offset -> channel: [0,384): c=ofs; [384,448): c=4096+ofs;
  // [448,512): c=8192+ofs; [512,515): c=12288+ofs;
  // [520,712): u=ofs-520, c=12803+(u&63)*3+(u>>6)  (L4 w^T at 520+o*64+ci)
  {
    float sm[12], st[16];
#pragma unroll
    for (int it = 0; it < 12; ++it) {
      const int ofs = sch + 64 * it;
      int c = 0;
      if (ofs < 384) c = ofs;
      else if (ofs < 448) c = 4096 + ofs;
      else if (ofs < 512) c = 8192 + ofs;
      else if (ofs < 515) c = 12288 + ofs;
      else if (ofs >= 520 && ofs < 712) {
        const int u = ofs - 520;
        c = 12803 + (u & 63) * 3 + (u >> 6);
      }
      sm[it] = (ofs < 712) ? gbase[(size_t)c * PLANE + sj] : 0.f;
    }
#pragma unroll
    for (int it = 0; it < 16; ++it)
      st[it] = gbase[(size_t)(384 + sch + 64 * it) * PLANE + sj];
#pragma unroll
    for (int it = 0; it < 12; ++it) {
      const int ofs = sch + 64 * it;
      if (ofs < 712) SM[sj * SMROW + ofs] = sm[it];
    }
#pragma unroll
    for (int it = 0; it < 16; ++it)
      CH[0][sj * CHROW + sch + 64 * it] = st[it];
  }
  asm volatile("s_waitcnt lgkmcnt(0)" ::: "memory");
  __builtin_amdgcn_s_barrier();

  // ---- PE features for this lane's pixel
  float f0, f1, f2, f3;
  {
    float s, c;
    sincosf(0.78539816339744830962f * dx, &s, &c); f0 = c; f1 = s;
    sincosf(0.78539816339744830962f * dy, &s, &c); f2 = c; f3 = s;
  }

  const float* __restrict__ smw = &SM[w * SMROW];  // wave-uniform -> broadcast

  // ---- L0: act[co] = leaky(b + f.w)
  float act[64], y[64];
#pragma unroll
  for (int q = 0; q < 16; ++q) {
    const float4 bq = *(const float4*)&smw[q * 4];
    const float4 w0 = *(const float4*)&smw[64 + q * 4];
    const float4 w1 = *(const float4*)&smw[128 + q * 4];
    const float4 w2 = *(const float4*)&smw[192 + q * 4];
    const float4 w3 = *(const float4*)&smw[256 + q * 4];
#pragma unroll
    for (int m = 0; m < 4; ++m) {
      float v = ((const float*)&bq)[m];
      v = fmaf(f0, ((const float*)&w0)[m], v);
      v = fmaf(f1, ((const float*)&w1)[m], v);
      v = fmaf(f2, ((const float*)&w2)[m], v);
      v = fmaf(f3, ((const float*)&w3)[m], v);
      act[q * 4 + m] = leaky(v);
    }
  }

  // ---- hidden layers: 4 chunks of 16 ci each, double-buffered in CH.
  float st[16];
  int cbase = 384;
  for (int l = 0; l < 3; ++l) {
    // y init = layer bias (broadcast from smalls)
#pragma unroll
    for (int q = 0; q < 16; ++q) {
      const float4 bq = *(const float4*)&smw[320 + l * 64 + q * 4];
      y[q * 4 + 0] = bq.x; y[q * 4 + 1] = bq.y;
      y[q * 4 + 2] = bq.z; y[q * 4 + 3] = bq.w;
    }

#define CHUNK(K)                                                          \
    {                                                                     \
      asm volatile("s_waitcnt lgkmcnt(0)" ::: "memory");                  \
      __builtin_amdgcn_s_barrier();                                       \
      const bool stg = (l < 2) || ((K) < 3);                              \
      const int cn = cbase + ((K) < 3 ? ((K) + 1) * 1024 : 4160);         \
      if (stg) {                                                          \
        _Pragma("unroll")                                                 \
        for (int it = 0; it < 16; ++it)                                   \
          st[it] = gbase[(size_t)(cn + sch + 64 * it) * PLANE + sj];      \
      }                                                                   \
      const float* bb = &CH[(K) & 1][w * CHROW];                          \
      _Pragma("unroll")                                                   \
      for (int cc = 0; cc < 16; ++cc) {                                   \
        const float a = act[(K) * 16 + cc];                               \
        _Pragma("unroll")                                                 \
        for (int q = 0; q < 16; ++q) {                                    \
          const float4 wq = *(const float4*)&bb[cc * 64 + q * 4];         \
          y[q * 4 + 0] = fmaf(a, wq.x, y[q * 4 + 0]);                     \
          y[q * 4 + 1] = fmaf(a, wq.y, y[q * 4 + 1]);                     \
          y[q * 4 + 2] = fmaf(a, wq.z, y[q * 4 + 2]);                     \
          y[q * 4 + 3] = fmaf(a, wq.w, y[q * 4 + 3]);                     \
        }                                                                 \
      }                                                                   \
      if (stg) {                                                          \
        float* wdst = &CH[((K) + 1) & 1][sj * CHROW];                     \
        _Pragma("unroll")                                                 \
        for (int it = 0; it < 16; ++it)                                   \
          wdst[sch + 64 * it] = st[it];                                   \
      }                                                                   \
    }

    CHUNK(0)
    CHUNK(1)
    CHUNK(2)
    CHUNK(3)
#undef CHUNK

    // layer end: act = leaky(y)
#pragma unroll
    for (int m = 0; m < 64; ++m) act[m] = leaky(y[m]);
    cbase += 4160;
  }

  // ---- L4 (64 -> 3) + tanh; w4 transposed in smalls at 520 + o*64 + ci
  float p0 = smw[512], p1 = smw[513], p2 = smw[514];
#pragma unroll
  for (int cg = 0; cg < 16; ++cg) {
    const float4 r0 = *(const float4*)&smw[520 + cg * 4];
    const float4 r1 = *(const float4*)&smw[520 + 64 + cg * 4];
    const float4 r2 = *(const float4*)&smw[520 + 128 + cg * 4];
#pragma unroll
    for (int u = 0; u < 4; ++u) {
      const float a = act[cg * 4 + u];
      p0 = fmaf(a, ((const float*)&r0)[u], p0);
      p1 = fmaf(a, ((const float*)&r1)[u], p1);
      p2 = fmaf(a, ((const float*)&r2)[u], p2);
    }
  }

  float* op = out + (size_t)b * 786432 +
              (size_t)(i * 8 + dy) * 512 + (size_t)((jg * 4 + w) * 8 + dx);
  op[0]      = tanhf(p0);
  op[262144] = tanhf(p1);
  op[524288] = tanhf(p2);
}

extern "C" void kernel_launch(void* const* d_in, const int* in_sizes, int n_in,
                              void* d_out, int out_size, void* d_ws, size_t ws_size,
                              hipStream_t stream) {
  (void)in_sizes; (void)n_in; (void)d_ws; (void)ws_size; (void)out_size;
  const float* lr = (const float*)d_in[1];  // d_in[0] = highres (unused by the math)
  float* out = (float*)d_out;
  hipLaunchKernelGGL(pqn, dim3(4096), dim3(256), 0, stream, lr, out);
}

// Round 13
// 12643.111 us; speedup vs baseline: 2.0097x; 2.0097x over previous
//
#include <hip/hip_runtime.h>
#include <math.h>

// PixelQueryNet v13: lane = pixel, wave = (cell, co-half), broadcast weights.
// Designed for <=128 VGPRs (R9-R12: allocator hard-caps at 128 and spills
// catastrophically; occupancy attributes are ignored). State per wave: y[32].
//
// Per low-res cell (b,i,j): MLP 4->64->64->64->64->3 (leaky 0.01, tanh) on the
// 64 pixels of its 8x8 tile; weights from lr_params[b,c,i,j] (channel stride
// PLANE=4096 floats).
//
// Block = 512 thr = 8 waves = 4 cells x 2 co-halves. Lane = pixel.
//  * Activations in LDS ACT[cell][ci][px]: reads/writes lane-contiguous b32
//    (conflict-free); 1 read per ci reused across 32 FMAs.
//  * Weights: LDS chunks CH[buf][cell][1024ch] (CHROW=1032 pad -> staging
//    writes 2-way); consumed as same-address ds_read_b128 broadcasts.
//  * Staging: b32, lane=(ch,j): 16 lines/wave-inst (vs the 64-line float4
//    gather that pinned R4-R8 at 37% VALUBusy); issued a full chunk (~2k cy)
//    before use. Siblings n..n+56 (same XCD, %8 round-robin) cover each 64B
//    line -> FETCH stays ideal (proven R4-R8).
//  * ~20 barriers total; 12 weight chunks of 16 ci x 32 co (512 FMA/wave).

static constexpr int PLANE = 4096;
static constexpr int NPAR  = 12995;
static constexpr int CHROW = 1032;   // padded per-cell chunk row (words)
static constexpr int SMROW = 712;    // per-cell smalls row (words)

__device__ __forceinline__ float leaky(float v) { return fmaxf(v, 0.01f * v); }

__global__ __launch_bounds__(512) void pqn(const float* __restrict__ lr,
                                           float* __restrict__ out) {
  __shared__ alignas(16) float ACT[4 * 4096];     // 65536 B [cell][ci][px]
  __shared__ alignas(16) float CH[2][4 * CHROW];  // 33024 B [buf][cell][ch]
  __shared__ alignas(16) float SM[4 * SMROW];     // 11392 B [cell][ofs]

  const int tid  = threadIdx.x;
  const int lane = tid & 63;          // pixel
  const int wv   = tid >> 6;
  const int cell = wv & 3;            // cell within block's j-quad
  const int half = wv >> 2;           // co/ci half
  const int ch0  = half * 32;
  const int dx = lane & 7, dy = lane >> 3;
  const int sj = tid & 3, sch = tid >> 2;   // staging (j, channel-offset)

  // ---- swizzle: 4 siblings (same XCD) cover one 64B weight line
  const int n  = blockIdx.x;
  const int e2 = (n >> 3) & 3;
  const int P  = (n & 7) | ((n >> 5) << 3);   // 0..511
  const int jq = ((P & 3) << 2) | e2;         // 0..15 (j-quad)
  const int i  = (P >> 2) & 63;
  const int b  = (P >> 8) & 1;

  const float* __restrict__ gbase =
      lr + (size_t)b * NPAR * PLANE + (size_t)(i * 64 + jq * 4);

  // ---- prologue staging: smalls + chunk 0.
  // smalls ofs -> channel: [0,384): c=ofs; [384,448): c=4096+ofs;
  // [448,512): c=8192+ofs; [512,515): c=12288+ofs;
  // [520,712): u=ofs-520, c=12803+(u&63)*3+(u>>6)   (L4 w^T at 520+o*64+ci)
  {
    float sm[6], st[8];
#pragma unroll
    for (int it = 0; it < 6; ++it) {
      const int ofs = sch + 128 * it;
      int c = 0;
      if (ofs < 384) c = ofs;
      else if (ofs < 448) c = 4096 + ofs;
      else if (ofs < 512) c = 8192 + ofs;
      else if (ofs < 515) c = 12288 + ofs;
      else if (ofs >= 520 && ofs < 712) {
        const int u = ofs - 520;
        c = 12803 + (u & 63) * 3 + (u >> 6);
      }
      sm[it] = (ofs < 712) ? gbase[(size_t)c * PLANE + sj] : 0.f;
    }
#pragma unroll
    for (int it = 0; it < 8; ++it)
      st[it] = gbase[(size_t)(384 + sch + 128 * it) * PLANE + sj];
#pragma unroll
    for (int it = 0; it < 6; ++it) {
      const int ofs = sch + 128 * it;
      if (ofs < 712) SM[sj * SMROW + ofs] = sm[it];
    }
#pragma unroll
    for (int it = 0; it < 8; ++it)
      CH[0][sj * CHROW + sch + 128 * it] = st[it];
  }
  asm volatile("s_waitcnt lgkmcnt(0)" ::: "memory");
  __builtin_amdgcn_s_barrier();

  // ---- PE features for this lane's pixel
  float f0, f1, f2, f3;
  {
    float s, c;
    sincosf(0.78539816339744830962f * dx, &s, &c); f0 = c; f1 = s;
    sincosf(0.78539816339744830962f * dy, &s, &c); f2 = c; f3 = s;
  }

  const float* __restrict__ smc = &SM[cell * SMROW];
  float y[32];

  // ---- L0: this wave's 32 co, straight to ACT
#pragma unroll
  for (int q = 0; q < 8; ++q) {
    const float4 bq = *(const float4*)&smc[ch0 + q * 4];
    const float4 w0 = *(const float4*)&smc[64 + ch0 + q * 4];
    const float4 w1 = *(const float4*)&smc[128 + ch0 + q * 4];
    const float4 w2 = *(const float4*)&smc[192 + ch0 + q * 4];
    const float4 w3 = *(const float4*)&smc[256 + ch0 + q * 4];
#pragma unroll
    for (int m = 0; m < 4; ++m) {
      float v = ((const float*)&bq)[m];
      v = fmaf(f0, ((const float*)&w0)[m], v);
      v = fmaf(f1, ((const float*)&w1)[m], v);
      v = fmaf(f2, ((const float*)&w2)[m], v);
      v = fmaf(f3, ((const float*)&w3)[m], v);
      ACT[cell * 4096 + (ch0 + q * 4 + m) * 64 + lane] = leaky(v);
    }
  }

  // ---- hidden layers: 4 chunks x 16 ci each, CH double-buffered
  for (int l = 0; l < 3; ++l) {
#pragma unroll
    for (int q = 0; q < 8; ++q) {
      const float4 bq = *(const float4*)&smc[320 + l * 64 + ch0 + q * 4];
      y[q * 4 + 0] = bq.x; y[q * 4 + 1] = bq.y;
      y[q * 4 + 2] = bq.z; y[q * 4 + 3] = bq.w;
    }

#define CHUNK(K)                                                          \
    {                                                                     \
      asm volatile("s_waitcnt lgkmcnt(0)" ::: "memory");                  \
      __builtin_amdgcn_s_barrier();                                       \
      const int g = l * 4 + (K);                                          \
      float st[8];                                                        \
      const bool stg = g < 11;                                            \
      if (stg) {                                                          \
        const int gn = g + 1;                                             \
        const int cn = 384 + (gn >> 2) * 4160 + (gn & 3) * 1024;          \
        _Pragma("unroll")                                                 \
        for (int it = 0; it < 8; ++it)                                    \
          st[it] = gbase[(size_t)(cn + sch + 128 * it) * PLANE + sj];     \
      }                                                                   \
      const float* bb = &CH[(K) & 1][cell * CHROW];                       \
      _Pragma("unroll")                                                   \
      for (int cc = 0; cc < 16; ++cc) {                                   \
        const float a = ACT[cell * 4096 + ((K) * 16 + cc) * 64 + lane];   \
        _Pragma("unroll")                                                 \
        for (int q = 0; q < 8; ++q) {                                     \
          const float4 wq = *(const float4*)&bb[cc * 64 + ch0 + q * 4];   \
          y[q * 4 + 0] = fmaf(a, wq.x, y[q * 4 + 0]);                     \
          y[q * 4 + 1] = fmaf(a, wq.y, y[q * 4 + 1]);                     \
          y[q * 4 + 2] = fmaf(a, wq.z, y[q * 4 + 2]);                     \
          y[q * 4 + 3] = fmaf(a, wq.w, y[q * 4 + 3]);                     \
        }                                                                 \
      }                                                                   \
      if (stg) {                                                          \
        float* wdst = &CH[((K) + 1) & 1][sj * CHROW];                     \
        _Pragma("unroll")                                                 \
        for (int it = 0; it < 8; ++it)                                    \
          wdst[sch + 128 * it] = st[it];                                  \
      }                                                                   \
    }

    CHUNK(0)
    CHUNK(1)
    CHUNK(2)
    CHUNK(3)
#undef CHUNK

    // flush: wait for peers' reads of old ACT, then publish leaky(y)
    asm volatile("s_waitcnt lgkmcnt(0)" ::: "memory");
    __builtin_amdgcn_s_barrier();
#pragma unroll
    for (int q = 0; q < 8; ++q)
#pragma unroll
      for (int m = 0; m < 4; ++m)
        ACT[cell * 4096 + (ch0 + q * 4 + m) * 64 + lane] = leaky(y[q * 4 + m]);
  }
  asm volatile("s_waitcnt lgkmcnt(0)" ::: "memory");
  __builtin_amdgcn_s_barrier();

  // ---- L4 (64 -> 3): partial over this wave's ci-half
  float p0 = 0.f, p1 = 0.f, p2 = 0.f;
#pragma unroll
  for (int cg = 0; cg < 8; ++cg) {
    const int cb = ch0 + cg * 4;
    const float4 r0 = *(const float4*)&smc[520 + cb];
    const float4 r1 = *(const float4*)&smc[520 + 64 + cb];
    const float4 r2 = *(const float4*)&smc[520 + 128 + cb];
#pragma unroll
    for (int u = 0; u < 4; ++u) {
      const float a = ACT[cell * 4096 + (cb + u) * 64 + lane];
      p0 = fmaf(a, ((const float*)&r0)[u], p0);
      p1 = fmaf(a, ((const float*)&r1)[u], p1);
      p2 = fmaf(a, ((const float*)&r2)[u], p2);
    }
  }
  asm volatile("s_waitcnt lgkmcnt(0)" ::: "memory");
  __builtin_amdgcn_s_barrier();      // CH reads all done -> reuse as partials
  if (half == 1) {
    float* PR = CH[0];
    PR[(cell * 3 + 0) * 64 + lane] = p0;
    PR[(cell * 3 + 1) * 64 + lane] = p1;
    PR[(cell * 3 + 2) * 64 + lane] = p2;
  }
  asm volatile("s_waitcnt lgkmcnt(0)" ::: "memory");
  __builtin_amdgcn_s_barrier();
  if (half == 0) {
    const float* PR = CH[0];
    const float q0 = tanhf(p0 + PR[(cell * 3 + 0) * 64 + lane] + smc[512]);
    const float q1 = tanhf(p1 + PR[(cell * 3 + 1) * 64 + lane] + smc[513]);
    const float q2 = tanhf(p2 + PR[(cell * 3 + 2) * 64 + lane] + smc[514]);
    float* op = out + (size_t)b * 786432 +
                (size_t)(i * 8 + dy) * 512 + (size_t)((jq * 4 + cell) * 8 + dx);
    op[0]      = q0;
    op[262144] = q1;
    op[524288] = q2;
  }
}

extern "C" void kernel_launch(void* const* d_in, const int* in_sizes, int n_in,
                              void* d_out, int out_size, void* d_ws, size_t ws_size,
                              hipStream_t stream) {
  (void)in_sizes; (void)n_in; (void)d_ws; (void)ws_size; (void)out_size;
  const float* lr = (const float*)d_in[1];  // d_in[0] = highres (unused by the math)
  float* out = (float*)d_out;
  hipLaunchKernelGGL(pqn, dim3(2048), dim3(512), 0, stream, lr, out);
}

// Round 14
// 252.171 us; speedup vs baseline: 100.7606x; 50.1370x over previous
//
#include <hip/hip_runtime.h>
#include <math.h>

// PixelQueryNet v14 = R6/v5 geometry (best: 370us) + 4-tile barrier groups.
// Per low-res cell (b,i,j): MLP 4->64->64->64->64->3 (leaky 0.01, tanh) on the
// 64 pixels of its 8x8 tile; weights from lr_params[b,c,i,j] (stride 4096 fl).
//
// Block = 256 thr = 4 cells(j) x 8 px-rows(pg) x 8 co-blocks(cob); y[8co][8px]
// in registers. A = two unpadded k-planes (lane-contiguous b128, conflict-free).
// Grid 2048; siblings n,n+8,n+16,n+24 (same XCD) take the four 16B j-quads of
// each 64B weight line -> FETCH ideal (proven R4-R8).
//
// v14 changes vs R6 (attacking the measured ~1000cy/slot sync residue):
//  * W quad-buffered: 2 barriers per 4 tiles (~56 total vs 103). Sequence:
//    [issue gathers g+1] [compute 4 tiles] [lgkm0+bar: reads done]
//    [flush if layer end] [write WB g+1] [lgkm0+bar: writes visible].
//  * L0 + biases via direct per-thread loads -> pipeline = 96 uniform tiles.
//  * Staging spread over all 256 threads (2 float4 each, sA/sB).
//  * launch_bounds(256,1): the only config that ever allocated >128 VGPR (R4).
//  * unroll 1 on the group loop (I$ protection).
// R9-R13 lesson: never let unrolled float4-LDS-read loops + big register state
// coexist (spill disasters at the 128-VGPR allocator target).

static constexpr int PLANE = 4096;
static constexpr int NPAR  = 12995;
static constexpr int WROW  = 160;   // quad starts j*40+2cob mod 32 -> <=2-way
static constexpr int AHI   = 8192;  // word offset of k4..7 plane

__device__ __forceinline__ float leaky(float v) { return fmaxf(v, 0.01f * v); }

// PE x-features, compile-time: cos/sin(2*pi*k/8), k = dx.
__device__ __forceinline__ constexpr float cx(int k) {
  constexpr float R = 0.70710678118654752f;
  const float t[8] = {1.f, R, 0.f, -R, -1.f, -R, 0.f, R};
  return t[k];
}
__device__ __forceinline__ constexpr float sx(int k) {
  constexpr float R = 0.70710678118654752f;
  const float t[8] = {0.f, R, 1.f, R, 0.f, -R, -1.f, -R};
  return t[k];
}

__global__ __launch_bounds__(256, 1) void pqn(const float* __restrict__ lr,
                                              float* __restrict__ out) {
  __shared__ alignas(16) float A[2 * AHI];        // 65536 B activations
  __shared__ alignas(16) float WB[4][4 * WROW];   // 10240 B weight quad-buffer

  const int tid = threadIdx.x;
  const int j   = tid & 3;
  const int pg  = (tid >> 2) & 7;      // pixel row (dy)
  const int cob = tid >> 5;            // 0..7

  // ---- swizzle: 4 siblings (same XCD) cover one 64B weight line
  const int n  = blockIdx.x;
  const int e2 = (n >> 3) & 3;
  const int P  = (n & 7) | ((n >> 5) << 3);   // 0..511
  const int jg = ((P & 3) << 2) | e2;         // 0..15
  const int i  = (P >> 2) & 63;
  const int b  = (P >> 8) & 1;

  const float* __restrict__ wb =
      lr + (size_t)b * NPAR * PLANE + (size_t)(i * 64 + jg * 4);
  const float* __restrict__ pt = wb + j;      // per-thread channel base

  float fyc, fys;
  sincosf(0.78539816339744830962f * pg, &fys, &fyc);

  const int abase = pg * 16 + j * 4;   // lane-contiguous A offset
  const int wrow  = j * WROW;
  const int sq    = tid >> 7;          // staging: which tile-pair half
  const int sc    = tid & 127;         // staging channel within tile

  // ---- prologue: staging for group 0 + direct L0/bias loads
  float4 sA, sB;
  {
    const size_t cb = 384;
    sA = *(const float4*)(wb + (cb + tid) * PLANE);         // tiles 0-1
    sB = *(const float4*)(wb + (cb + 256 + tid) * PLANE);   // tiles 2-3
  }
  float l0b[8], l0w[32], bb[8];
#pragma unroll
  for (int m = 0; m < 8; ++m) l0b[m] = pt[(size_t)(cob * 8 + m) * PLANE];
#pragma unroll
  for (int f = 0; f < 4; ++f)
#pragma unroll
    for (int m = 0; m < 8; ++m)
      l0w[f * 8 + m] = pt[(size_t)(64 + f * 64 + cob * 8 + m) * PLANE];
#pragma unroll
  for (int m = 0; m < 8; ++m) bb[m] = pt[(size_t)(320 + cob * 8 + m) * PLANE];

  // ---- L0 compute -> A
#pragma unroll
  for (int col = 0; col < 8; ++col) {
    float t[8];
#pragma unroll
    for (int k = 0; k < 8; ++k) {
      float v = l0b[col];
      v = fmaf(cx(k), l0w[col], v);
      v = fmaf(sx(k), l0w[8 + col], v);
      v = fmaf(fyc,  l0w[16 + col], v);
      v = fmaf(fys,  l0w[24 + col], v);
      t[k] = leaky(v);
    }
    float4 v0, v1;
    v0.x = t[0]; v0.y = t[1]; v0.z = t[2]; v0.w = t[3];
    v1.x = t[4]; v1.y = t[5]; v1.z = t[6]; v1.w = t[7];
    *(float4*)&A[(cob * 8 + col) * 128 + abase]       = v0;
    *(float4*)&A[(cob * 8 + col) * 128 + abase + AHI] = v1;
  }
  // stage group-0 weights into WB
#pragma unroll
  for (int jj = 0; jj < 4; ++jj) {
    WB[sq][jj * WROW + sc]     = ((const float*)&sA)[jj];
    WB[2 + sq][jj * WROW + sc] = ((const float*)&sB)[jj];
  }
  asm volatile("s_waitcnt lgkmcnt(0)" ::: "memory");
  __builtin_amdgcn_s_barrier();
  __builtin_amdgcn_sched_barrier(0);

  float y[64];
#pragma unroll
  for (int m = 0; m < 64; ++m) y[m] = 0.f;

  // ---- 24 groups of 4 tiles (8 ci); 96 weight tiles = 3 layers x 32
#pragma unroll 1
  for (int g = 0; g < 24; ++g) {
    // issue next group's gathers (full-group lookahead hides L2/HBM service)
    if (g < 23) {
      const int gn = g + 1;
      const size_t cb = 384 + (size_t)(gn >> 3) * 4160 + (size_t)(gn & 7) * 512;
      sA = *(const float4*)(wb + (cb + tid) * PLANE);
      sB = *(const float4*)(wb + (cb + 256 + tid) * PLANE);
    }
    // compute 4 tiles from WB[0..3]
    const int r0 = (g & 7) * 8;          // ci base of this group
#pragma unroll
    for (int q = 0; q < 4; ++q) {
      const float* Wt = WB[q];
#pragma unroll
      for (int cl = 0; cl < 2; ++cl) {
        const int ci = r0 + q * 2 + cl;
        const float4 a0 = *(const float4*)&A[ci * 128 + abase];
        const float4 a1 = *(const float4*)&A[ci * 128 + abase + AHI];
        const float4 w0 = *(const float4*)&Wt[wrow + cl * 64 + cob * 8];
        const float4 w1 = *(const float4*)&Wt[wrow + cl * 64 + cob * 8 + 4];
        const float av[8] = {a0.x, a0.y, a0.z, a0.w, a1.x, a1.y, a1.z, a1.w};
        const float wv[8] = {w0.x, w0.y, w0.z, w0.w, w1.x, w1.y, w1.z, w1.w};
#pragma unroll
        for (int col = 0; col < 8; ++col)
#pragma unroll
          for (int k = 0; k < 8; ++k)
            y[col * 8 + k] = fmaf(av[k], wv[col], y[col * 8 + k]);
      }
    }
    asm volatile("s_waitcnt lgkmcnt(0)" ::: "memory");
    __builtin_amdgcn_s_barrier();        // everyone's A/WB reads done
    __builtin_amdgcn_sched_barrier(0);

    if ((g & 7) == 7) {                  // layer end: bias + leaky -> A
      const int l = g >> 3;
#pragma unroll
      for (int col = 0; col < 8; ++col) {
        float4 v0, v1;
        v0.x = leaky(y[col * 8 + 0] + bb[col]);
        v0.y = leaky(y[col * 8 + 1] + bb[col]);
        v0.z = leaky(y[col * 8 + 2] + bb[col]);
        v0.w = leaky(y[col * 8 + 3] + bb[col]);
        v1.x = leaky(y[col * 8 + 4] + bb[col]);
        v1.y = leaky(y[col * 8 + 5] + bb[col]);
        v1.z = leaky(y[col * 8 + 6] + bb[col]);
        v1.w = leaky(y[col * 8 + 7] + bb[col]);
        *(float4*)&A[(cob * 8 + col) * 128 + abase]       = v0;
        *(float4*)&A[(cob * 8 + col) * 128 + abase + AHI] = v1;
      }
#pragma unroll
      for (int m = 0; m < 64; ++m) y[m] = 0.f;
      if (l < 2) {
#pragma unroll
        for (int m = 0; m < 8; ++m)
          bb[m] = pt[(size_t)(320 + (l + 1) * 4160 + cob * 8 + m) * PLANE];
      }
    }
    if (g < 23) {                        // publish next group's weights
#pragma unroll
      for (int jj = 0; jj < 4; ++jj) {
        WB[sq][jj * WROW + sc]     = ((const float*)&sA)[jj];
        WB[2 + sq][jj * WROW + sc] = ((const float*)&sB)[jj];
      }
    }
    asm volatile("s_waitcnt lgkmcnt(0)" ::: "memory");
    __builtin_amdgcn_s_barrier();        // A-flush + WB writes visible
    __builtin_amdgcn_sched_barrier(0);
  }

  // ---- epilogue: L4 (64 -> 3) + tanh
  float po[24];
#pragma unroll
  for (int m = 0; m < 24; ++m) po[m] = 0.f;
#pragma unroll
  for (int cl = 0; cl < 8; ++cl) {
    const int ci = cob * 8 + cl;
    const float4 a0 = *(const float4*)&A[ci * 128 + abase];
    const float4 a1 = *(const float4*)&A[ci * 128 + abase + AHI];
#pragma unroll
    for (int o = 0; o < 3; ++o) {
      const float w = pt[(size_t)(12803 + ci * 3 + o) * PLANE];
      po[o * 8 + 0] = fmaf(a0.x, w, po[o * 8 + 0]);
      po[o * 8 + 1] = fmaf(a0.y, w, po[o * 8 + 1]);
      po[o * 8 + 2] = fmaf(a0.z, w, po[o * 8 + 2]);
      po[o * 8 + 3] = fmaf(a0.w, w, po[o * 8 + 3]);
      po[o * 8 + 4] = fmaf(a1.x, w, po[o * 8 + 4]);
      po[o * 8 + 5] = fmaf(a1.y, w, po[o * 8 + 5]);
      po[o * 8 + 6] = fmaf(a1.z, w, po[o * 8 + 6]);
      po[o * 8 + 7] = fmaf(a1.w, w, po[o * 8 + 7]);
    }
  }
  asm volatile("s_waitcnt lgkmcnt(0)" ::: "memory");
  __builtin_amdgcn_s_barrier();        // all A reads done -> reuse A
  float* R = A;
#pragma unroll
  for (int m = 0; m < 24; m += 4)
    *(float4*)&R[tid * 28 + m] = *(float4*)&po[m];
  asm volatile("s_waitcnt lgkmcnt(0)" ::: "memory");
  __builtin_amdgcn_s_barrier();
  __builtin_amdgcn_sched_barrier(0);

  if (cob == 0) {                      // tid < 32: one (j, pg) per thread
#pragma unroll
    for (int o = 0; o < 3; ++o) {
      const float bias = pt[(size_t)(12800 + o) * PLANE];
      float s[8];
#pragma unroll
      for (int k = 0; k < 8; ++k) s[k] = bias;
#pragma unroll
      for (int cb = 0; cb < 8; ++cb) {
#pragma unroll
        for (int k = 0; k < 8; ++k)
          s[k] += R[(cb * 32 + tid) * 28 + o * 8 + k];
      }
      float4 v0, v1;
      v0.x = tanhf(s[0]); v0.y = tanhf(s[1]); v0.z = tanhf(s[2]); v0.w = tanhf(s[3]);
      v1.x = tanhf(s[4]); v1.y = tanhf(s[5]); v1.z = tanhf(s[6]); v1.w = tanhf(s[7]);
      float* op = out + (size_t)b * 786432 + (size_t)o * 262144 +
                  (size_t)(i * 8 + pg) * 512 + (size_t)((jg * 4 + j) * 8);
      *(float4*)op = v0;
      *(float4*)(op + 4) = v1;
    }
  }
}

extern "C" void kernel_launch(void* const* d_in, const int* in_sizes, int n_in,
                              void* d_out, int out_size, void* d_ws, size_t ws_size,
                              hipStream_t stream) {
  (void)in_sizes; (void)n_in; (void)d_ws; (void)ws_size; (void)out_size;
  const float* lr = (const float*)d_in[1];  // d_in[0] = highres (unused by the math)
  float* out = (float*)d_out;
  hipLaunchKernelGGL(pqn, dim3(2048), dim3(256), 0, stream, lr, out);
}